// Round 1
// baseline (103.239 us; speedup 1.0000x reference)
//
#include <hip/hip_runtime.h>

#define AS1 __attribute__((address_space(1)))
#define AS3 __attribute__((address_space(3)))

typedef __bf16 bf16x8 __attribute__((ext_vector_type(8)));
typedef float f32x4 __attribute__((ext_vector_type(4)));

static constexpr int C = 768;
static constexpr int NB = 128;    // N1 == N2
static constexpr int S  = 256;    // W*H
static constexpr int XY_ELEMS  = NB * NB * S;  // 4194304
static constexpr int XSQ_ELEMS = NB * S;       // 32768

// ---------------------------------------------------------------------------
// Pass 1: for each tensor (x,y): transpose [n][c][s] fp32 -> [s][n][c] bf16,
//         and compute mean_c of squares -> xx/yy region of d_out.
// grid: 1024 blocks (tensor, n, s-tile of 64), 256 threads.
// ---------------------------------------------------------------------------
__global__ __launch_bounds__(256) void pass1(const float* __restrict__ x,
                                             const float* __restrict__ y,
                                             unsigned short* __restrict__ xb,
                                             unsigned short* __restrict__ yb,
                                             float* __restrict__ out) {
  int b      = blockIdx.x;
  int tensor = b >> 9;          // 0 = x, 1 = y
  int local  = b & 511;
  int n      = local >> 2;      // 0..127
  int st     = local & 3;       // s-tile of 64

  const float*    src  = tensor ? y  : x;
  unsigned short* dst  = tensor ? yb : xb;
  float*          sqo  = out + XY_ELEMS + tensor * XSQ_ELEMS;

  __shared__ float tile[32][65];   // [c_local][s_local] fp32, +1 pad
  __shared__ float part[16][64];

  int t  = threadIdx.x;
  int cl = t >> 4;               // 0..15  (load-side c row within half-chunk)
  int s4 = (t & 15) * 4;         // 0..60  (load-side s offset, float4)
  int sl = t >> 2;               // 0..63  (store-side s row)
  int cq = t & 3;                // 0..3   (store-side c group of 8)

  float a0 = 0.f, a1 = 0.f, a2 = 0.f, a3 = 0.f;

  const float*    srcn = src + (size_t)n * (C * S) + st * 64;
  unsigned short* dstn = dst + (size_t)n * C;

  for (int ch = 0; ch < 24; ++ch) {
    int c0 = ch * 32;
    // ---- coalesced load: 32 c-rows x 64 s (float4 per thread, 2 sub-iters)
#pragma unroll
    for (int q = 0; q < 2; ++q) {
      int c = c0 + q * 16 + cl;
      float4 v = *reinterpret_cast<const float4*>(srcn + (size_t)c * S + s4);
      tile[q * 16 + cl][s4 + 0] = v.x;
      tile[q * 16 + cl][s4 + 1] = v.y;
      tile[q * 16 + cl][s4 + 2] = v.z;
      tile[q * 16 + cl][s4 + 3] = v.w;
      a0 += v.x * v.x; a1 += v.y * v.y; a2 += v.z * v.z; a3 += v.w * v.w;
    }
    __syncthreads();
    // ---- transposed bf16 store: 64 s-rows x 32 c, 8 bf16 (16B) per thread
    {
      alignas(16) unsigned short u[8];
#pragma unroll
      for (int i = 0; i < 8; ++i) {
        float f = tile[cq * 8 + i][sl];
        unsigned fu = __float_as_uint(f);
        unsigned r  = fu + 0x7fffu + ((fu >> 16) & 1u);  // RNE
        u[i] = (unsigned short)(r >> 16);
      }
      int sg = st * 64 + sl;
      *reinterpret_cast<uint4*>(dstn + (size_t)sg * (NB * C) + c0 + cq * 8) =
          *reinterpret_cast<const uint4*>(u);
    }
    __syncthreads();
  }

  // ---- reduce per-s square sums (16 c-lanes -> 1) and write mean
  part[t >> 4][(t & 15) * 4 + 0] = a0;
  part[t >> 4][(t & 15) * 4 + 1] = a1;
  part[t >> 4][(t & 15) * 4 + 2] = a2;
  part[t >> 4][(t & 15) * 4 + 3] = a3;
  __syncthreads();
  if (t < 64) {
    float ssum = 0.f;
#pragma unroll
    for (int i = 0; i < 16; ++i) ssum += part[i][t];
    sqo[n * S + st * 64 + t] = ssum * (1.0f / 768.0f);
  }
}

// ---------------------------------------------------------------------------
// Pass 2: per spatial s, C_s = (1/768) * A_s * B_s^T  (A=xb[s], B=yb[s], both
// [128][768] bf16 k-contiguous). m97 structure: 128x128 tile, BK=64,
// global_load_lds width 16 with pre-swizzled source, swizzled ds_read_b128.
// grid: 256 blocks x 256 threads (4 waves, 2x2 over 64x64 sub-tiles).
// ---------------------------------------------------------------------------
__global__ __launch_bounds__(256) void pass2(const unsigned short* __restrict__ xb,
                                             const unsigned short* __restrict__ yb,
                                             float* __restrict__ out) {
  int bid = blockIdx.x;
  // XCD-aware: each XCD gets a contiguous 32-s chunk so the 16 writers of
  // each 64B output line share one L2 (write-merge).
  int s = ((bid & 7) << 5) | (bid >> 3);

  const unsigned short* A = xb + (size_t)s * (NB * C);
  const unsigned short* B = yb + (size_t)s * (NB * C);

  __shared__ unsigned short As[128 * 64];
  __shared__ unsigned short Bs[128 * 64];

  int t    = threadIdx.x;
  int lane = t & 63;
  int w    = t >> 6;
  int wn   = w >> 1;   // row half (n)
  int wm   = w & 1;    // col half (m)

  f32x4 acc[4][4] = {};

  for (int k0 = 0; k0 < 12; ++k0) {
    // ---- stage A,B tiles: 128 rows x 64 k bf16 each, 16B per lane-issue.
    // LDS linear; global source chunk pre-swizzled: j_global = j ^ (row&7).
#pragma unroll
    for (int i = 0; i < 4; ++i) {
      int ci  = i * 256 + t;        // 0..1023 = row*8 + j
      int row = ci >> 3;
      int j   = ci & 7;
      int js  = j ^ (row & 7);
      const unsigned short* gpA = A + row * C + k0 * 64 + js * 8;
      const unsigned short* gpB = B + row * C + k0 * 64 + js * 8;
      __builtin_amdgcn_global_load_lds((const AS1 unsigned int*)gpA,
                                       (AS3 unsigned int*)((char*)As + ci * 16),
                                       16, 0, 0);
      __builtin_amdgcn_global_load_lds((const AS1 unsigned int*)gpB,
                                       (AS3 unsigned int*)((char*)Bs + ci * 16),
                                       16, 0, 0);
    }
    __syncthreads();

    // ---- 2 MFMA k-halves of 32
#pragma unroll
    for (int ks = 0; ks < 2; ++ks) {
      bf16x8 af[4], bfr[4];
      int jg = ks * 4 + (lane >> 4);
#pragma unroll
      for (int mi = 0; mi < 4; ++mi) {
        int row = wn * 64 + mi * 16 + (lane & 15);
        af[mi] = *reinterpret_cast<const bf16x8*>(
            (char*)As + row * 128 + ((jg ^ (row & 7)) * 16));
      }
#pragma unroll
      for (int nj = 0; nj < 4; ++nj) {
        int row = wm * 64 + nj * 16 + (lane & 15);
        bfr[nj] = *reinterpret_cast<const bf16x8*>(
            (char*)Bs + row * 128 + ((jg ^ (row & 7)) * 16));
      }
#pragma unroll
      for (int mi = 0; mi < 4; ++mi)
#pragma unroll
        for (int nj = 0; nj < 4; ++nj)
          acc[mi][nj] = __builtin_amdgcn_mfma_f32_16x16x32_bf16(
              af[mi], bfr[nj], acc[mi][nj], 0, 0, 0);
    }
    __syncthreads();
  }

  // ---- epilogue: C/D layout col=lane&15, row=(lane>>4)*4+reg (m89-verified)
  const float inv = 1.0f / 768.0f;
#pragma unroll
  for (int mi = 0; mi < 4; ++mi) {
#pragma unroll
    for (int nj = 0; nj < 4; ++nj) {
#pragma unroll
      for (int r = 0; r < 4; ++r) {
        int n = wn * 64 + mi * 16 + (lane >> 4) * 4 + r;  // x index (A rows)
        int m = wm * 64 + nj * 16 + (lane & 15);          // y index (B cols)
        out[((size_t)n * NB + m) * S + s] = acc[mi][nj][r] * inv;
      }
    }
  }
}

extern "C" void kernel_launch(void* const* d_in, const int* in_sizes, int n_in,
                              void* d_out, int out_size, void* d_ws, size_t ws_size,
                              hipStream_t stream) {
  const float* x = (const float*)d_in[0];
  const float* y = (const float*)d_in[1];
  float* out = (float*)d_out;

  unsigned short* xb = (unsigned short*)d_ws;                 // [256][128][768] bf16
  unsigned short* yb = xb + (size_t)S * NB * C;               // 50,331,648 B each

  pass1<<<1024, 256, 0, stream>>>(x, y, xb, yb, out);
  pass2<<<256, 256, 0, stream>>>(xb, yb, out);
}

// Round 2
// 98.014 us; speedup vs baseline: 1.0533x; 1.0533x over previous
//
#include <hip/hip_runtime.h>

#define AS1 __attribute__((address_space(1)))
#define AS3 __attribute__((address_space(3)))

typedef __bf16 bf16x8 __attribute__((ext_vector_type(8)));
typedef float f32x4 __attribute__((ext_vector_type(4)));

static constexpr int C = 768;
static constexpr int NB = 128;    // N1 == N2
static constexpr int S  = 256;    // W*H
static constexpr int XY_ELEMS  = NB * NB * S;  // 4194304
static constexpr int XSQ_ELEMS = NB * S;       // 32768

// ---------------------------------------------------------------------------
// Pass 1: transpose [n][c][s] fp32 -> [s][n][c] bf16 + fused square-mean.
// grid: 1024 blocks = (tensor, n, s-tile of 64), 256 threads.
// Pipelined: 12 chunks of 64c x 64s, double-buffered LDS, ONE raw s_barrier
// per chunk draining lgkmcnt only (prefetch vmcnt stays in flight).
// LDS layout: word(c,s) = c*68 + (s ^ ((c>>4)<<3))  -- 16B-aligned b128
// writes, read-phase conflicts reduced to 2-way (free).
// ---------------------------------------------------------------------------
__global__ __launch_bounds__(256) void pass1(const float* __restrict__ x,
                                             const float* __restrict__ y,
                                             unsigned short* __restrict__ xb,
                                             unsigned short* __restrict__ yb,
                                             float* __restrict__ out) {
  const int b      = blockIdx.x;
  const int tensor = b >> 9;          // 0 = x, 1 = y
  const int local  = b & 511;
  const int n      = local >> 2;      // 0..127
  const int st     = local & 3;       // s-tile of 64

  const float*    src = tensor ? y  : x;
  unsigned short* dst = tensor ? yb : xb;
  float*          sqo = out + XY_ELEMS + tensor * XSQ_ELEMS;

  __shared__ float tile[2][64 * 68];   // 2 x 17408 B
  __shared__ float part[16][64];

  const int t  = threadIdx.x;
  const int cl = t >> 4;               // 0..15 (load-side c row)
  const int s4 = (t & 15) * 4;         // 0..60 (load-side s offset)
  const int sl = t >> 2;               // 0..63 (store-side s row)
  const int cq = t & 3;                // 0..3  (store-side c group of 16)

  const float* srcn = src + (size_t)n * (C * S) + st * 64;
  unsigned short* dstn =
      dst + ((size_t)(st * 64 + sl) * NB + n) * C + cq * 16;

  f32x4 acc = {0.f, 0.f, 0.f, 0.f};
  f32x4 cur[4];

  // prologue: load chunk 0 (nontemporal: don't evict bf16 ws from L3)
#pragma unroll
  for (int sI = 0; sI < 4; ++sI) {
    const float* p = srcn + (size_t)(sI * 16 + cl) * S + s4;
    cur[sI] = __builtin_nontemporal_load(reinterpret_cast<const f32x4*>(p));
  }

#pragma unroll
  for (int ch = 0; ch < 12; ++ch) {
    float* tb = tile[ch & 1];

    // ---- squares + vectorized LDS write (b128, swizzled)
#pragma unroll
    for (int sI = 0; sI < 4; ++sI) {
      acc += cur[sI] * cur[sI];
      int c_loc = sI * 16 + cl;
      *reinterpret_cast<f32x4*>(&tb[c_loc * 68 + (s4 ^ (sI << 3))]) = cur[sI];
    }

    // ---- prefetch next chunk (stays in flight across the barrier)
    if (ch < 11) {
#pragma unroll
      for (int sI = 0; sI < 4; ++sI) {
        const float* p =
            srcn + (size_t)((ch + 1) * 64 + sI * 16 + cl) * S + s4;
        cur[sI] =
            __builtin_nontemporal_load(reinterpret_cast<const f32x4*>(p));
      }
    }

    // ---- barrier: drain LDS writes only, NOT the prefetch vmcnt
    asm volatile("s_waitcnt lgkmcnt(0)" ::: "memory");
    __builtin_amdgcn_s_barrier();

    // ---- transposed read + bf16 cvt + full-line (128B/s-row) store
    alignas(16) unsigned short u[16];
#pragma unroll
    for (int i = 0; i < 16; ++i) {
      int c_loc = cq * 16 + i;
      float f   = tb[c_loc * 68 + (sl ^ (cq << 3))];
      unsigned fu = __float_as_uint(f);
      unsigned r  = fu + 0x7fffu + ((fu >> 16) & 1u);  // RNE
      u[i] = (unsigned short)(r >> 16);
    }
    *reinterpret_cast<uint4*>(dstn + ch * 64) =
        *reinterpret_cast<const uint4*>(&u[0]);
    *reinterpret_cast<uint4*>(dstn + ch * 64 + 8) =
        *reinterpret_cast<const uint4*>(&u[8]);
    // no second barrier needed: next iter writes the OTHER buffer; this
    // buffer is rewritten only after the next barrier (reads drained by
    // their own consumption before any thread reaches it).
  }

  // ---- square-mean reduction (part[] is a separate LDS region)
#pragma unroll
  for (int j = 0; j < 4; ++j) part[cl][(t & 15) * 4 + j] = acc[j];
  __syncthreads();
  if (t < 64) {
    float ssum = 0.f;
#pragma unroll
    for (int i = 0; i < 16; ++i) ssum += part[i][t];
    sqo[n * S + st * 64 + t] = ssum * (1.0f / 768.0f);
  }
}

// ---------------------------------------------------------------------------
// Pass 2 (unchanged, verified): per spatial s, C_s = (1/768) * A_s * B_s^T.
// m97 structure: 128x128 tile, BK=64, global_load_lds width 16 with
// pre-swizzled source, swizzled ds_read_b128, mfma_f32_16x16x32_bf16.
// ---------------------------------------------------------------------------
__global__ __launch_bounds__(256) void pass2(const unsigned short* __restrict__ xb,
                                             const unsigned short* __restrict__ yb,
                                             float* __restrict__ out) {
  int bid = blockIdx.x;
  int s = ((bid & 7) << 5) | (bid >> 3);   // XCD-aware swizzle (bijective)

  const unsigned short* A = xb + (size_t)s * (NB * C);
  const unsigned short* B = yb + (size_t)s * (NB * C);

  __shared__ unsigned short As[128 * 64];
  __shared__ unsigned short Bs[128 * 64];

  int t    = threadIdx.x;
  int lane = t & 63;
  int w    = t >> 6;
  int wn   = w >> 1;
  int wm   = w & 1;

  f32x4 acc[4][4] = {};

  for (int k0 = 0; k0 < 12; ++k0) {
#pragma unroll
    for (int i = 0; i < 4; ++i) {
      int ci  = i * 256 + t;        // row*8 + j
      int row = ci >> 3;
      int j   = ci & 7;
      int js  = j ^ (row & 7);
      const unsigned short* gpA = A + row * C + k0 * 64 + js * 8;
      const unsigned short* gpB = B + row * C + k0 * 64 + js * 8;
      __builtin_amdgcn_global_load_lds((const AS1 unsigned int*)gpA,
                                       (AS3 unsigned int*)((char*)As + ci * 16),
                                       16, 0, 0);
      __builtin_amdgcn_global_load_lds((const AS1 unsigned int*)gpB,
                                       (AS3 unsigned int*)((char*)Bs + ci * 16),
                                       16, 0, 0);
    }
    __syncthreads();

#pragma unroll
    for (int ks = 0; ks < 2; ++ks) {
      bf16x8 af[4], bfr[4];
      int jg = ks * 4 + (lane >> 4);
#pragma unroll
      for (int mi = 0; mi < 4; ++mi) {
        int row = wn * 64 + mi * 16 + (lane & 15);
        af[mi] = *reinterpret_cast<const bf16x8*>(
            (char*)As + row * 128 + ((jg ^ (row & 7)) * 16));
      }
#pragma unroll
      for (int nj = 0; nj < 4; ++nj) {
        int row = wm * 64 + nj * 16 + (lane & 15);
        bfr[nj] = *reinterpret_cast<const bf16x8*>(
            (char*)Bs + row * 128 + ((jg ^ (row & 7)) * 16));
      }
#pragma unroll
      for (int mi = 0; mi < 4; ++mi)
#pragma unroll
        for (int nj = 0; nj < 4; ++nj)
          acc[mi][nj] = __builtin_amdgcn_mfma_f32_16x16x32_bf16(
              af[mi], bfr[nj], acc[mi][nj], 0, 0, 0);
    }
    __syncthreads();
  }

  const float inv = 1.0f / 768.0f;
#pragma unroll
  for (int mi = 0; mi < 4; ++mi) {
#pragma unroll
    for (int nj = 0; nj < 4; ++nj) {
#pragma unroll
      for (int r = 0; r < 4; ++r) {
        int n = wn * 64 + mi * 16 + (lane >> 4) * 4 + r;  // x index
        int m = wm * 64 + nj * 16 + (lane & 15);          // y index
        out[((size_t)n * NB + m) * S + s] = acc[mi][nj][r] * inv;
      }
    }
  }
}

extern "C" void kernel_launch(void* const* d_in, const int* in_sizes, int n_in,
                              void* d_out, int out_size, void* d_ws, size_t ws_size,
                              hipStream_t stream) {
  const float* x = (const float*)d_in[0];
  const float* y = (const float*)d_in[1];
  float* out = (float*)d_out;

  unsigned short* xb = (unsigned short*)d_ws;       // [256][128][768] bf16
  unsigned short* yb = xb + (size_t)S * NB * C;

  pass1<<<1024, 256, 0, stream>>>(x, y, xb, yb, out);
  pass2<<<256, 256, 0, stream>>>(xb, yb, out);
}